// Round 1
// baseline (1253.824 us; speedup 1.0000x reference)
//
#include <hip/hip_runtime.h>
#include <stdint.h>

typedef __attribute__((ext_vector_type(8))) short short8;
typedef __attribute__((ext_vector_type(4))) float floatx4;

#define SEQ    2048
#define HID    4096
#define NHEAD  32
#define HDIMV  128
#define PROJN  12288

__device__ __forceinline__ unsigned short f2bf(float f) {
  union { float f; unsigned u; } v; v.f = f;
  unsigned r = (v.u + 0x7fffu + ((v.u >> 16) & 1u)) >> 16;
  return (unsigned short)r;
}

// -------------------- fp32 -> bf16 convert --------------------
__global__ __launch_bounds__(256) void cvt_kernel(const float* __restrict__ src,
                                                  unsigned short* __restrict__ dst) {
  long i = ((long)blockIdx.x * 256 + threadIdx.x) * 8;
  float4 a = *(const float4*)(src + i);
  float4 b = *(const float4*)(src + i + 4);
  short8 o;
  o[0] = (short)f2bf(a.x); o[1] = (short)f2bf(a.y);
  o[2] = (short)f2bf(a.z); o[3] = (short)f2bf(a.w);
  o[4] = (short)f2bf(b.x); o[5] = (short)f2bf(b.y);
  o[6] = (short)f2bf(b.z); o[7] = (short)f2bf(b.w);
  *(short8*)(dst + i) = o;
}

// -------------------- async 16B global->LDS --------------------
__device__ __forceinline__ void g2l16(const void* g, void* l) {
  __builtin_amdgcn_global_load_lds(
      (const __attribute__((address_space(1))) void*)g,
      (__attribute__((address_space(3))) void*)l, 16, 0, 0);
}

// -------------------- NT GEMM: C[MxN] = A[MxK] * B[NxK]^T (bf16 in, bf16/f32 out) ---
// 128x128 tile, BK=32, 256 threads = 4 waves, each wave 64x64 via 4x4 of 16x16x32.
// LDS chunk-major layout: chunk id = (k>>3)*128 + row, 8 bf16 per chunk ->
// ds_read_b128 frag loads are bank-conflict-free and global_load_lds dest is
// wave-uniform base + lane*16 as required.
template<int OUT_F32>
__global__ __launch_bounds__(256, 2) void gemm_nt(
    const unsigned short* __restrict__ A,
    const unsigned short* __restrict__ B,
    void* __restrict__ C, int M, int N, int K) {
  __shared__ __align__(16) unsigned short As[4096];
  __shared__ __align__(16) unsigned short Bs[4096];
  const int t = threadIdx.x;
  const int wave = t >> 6;
  const int lane = t & 63;
  const int m0 = blockIdx.y * 128;
  const int n0 = blockIdx.x * 128;
  const int c0 = t, c1 = t + 256;
  const unsigned short* a0 = A + (long)(m0 + (c0 & 127)) * K + (c0 >> 7) * 8;
  const unsigned short* a1 = A + (long)(m0 + (c1 & 127)) * K + (c1 >> 7) * 8;
  const unsigned short* b0 = B + (long)(n0 + (c0 & 127)) * K + (c0 >> 7) * 8;
  const unsigned short* b1 = B + (long)(n0 + (c1 & 127)) * K + (c1 >> 7) * 8;
  unsigned short* asl0 = As + wave * 64 * 8;
  unsigned short* asl1 = As + (256 + wave * 64) * 8;
  unsigned short* bsl0 = Bs + wave * 64 * 8;
  unsigned short* bsl1 = Bs + (256 + wave * 64) * 8;

  const int mw = (wave >> 1) * 64;
  const int nw = (wave & 1) * 64;
  const int lq = lane & 15, lg = lane >> 4;
  const int faoff = (lg * 128 + mw + lq) * 8;
  const int fboff = (lg * 128 + nw + lq) * 8;

  floatx4 zero = {0.f, 0.f, 0.f, 0.f};
  floatx4 acc[4][4];
  for (int i = 0; i < 4; i++)
    for (int j = 0; j < 4; j++) acc[i][j] = zero;

  for (int k0 = 0; k0 < K; k0 += 32) {
    __syncthreads();
    g2l16(a0 + k0, asl0);
    g2l16(a1 + k0, asl1);
    g2l16(b0 + k0, bsl0);
    g2l16(b1 + k0, bsl1);
    __syncthreads();
    short8 af[4], bfr[4];
#pragma unroll
    for (int i = 0; i < 4; i++) af[i] = *(const short8*)(As + faoff + i * 128);
#pragma unroll
    for (int j = 0; j < 4; j++) bfr[j] = *(const short8*)(Bs + fboff + j * 128);
#pragma unroll
    for (int i = 0; i < 4; i++)
#pragma unroll
      for (int j = 0; j < 4; j++)
        acc[i][j] = __builtin_amdgcn_mfma_f32_16x16x32_bf16(af[i], bfr[j], acc[i][j], 0, 0, 0);
  }

  const int row0 = m0 + mw + lg * 4;
  const int col0 = n0 + nw + lq;
  if (OUT_F32) {
    float* Cf = (float*)C;
#pragma unroll
    for (int i = 0; i < 4; i++)
#pragma unroll
      for (int j = 0; j < 4; j++)
#pragma unroll
        for (int r = 0; r < 4; r++)
          Cf[(long)(row0 + i * 16 + r) * N + col0 + j * 16] = acc[i][j][r];
  } else {
    unsigned short* Cb = (unsigned short*)C;
#pragma unroll
    for (int i = 0; i < 4; i++)
#pragma unroll
      for (int j = 0; j < 4; j++)
#pragma unroll
        for (int r = 0; r < 4; r++)
          Cb[(long)(row0 + i * 16 + r) * N + col0 + j * 16] = f2bf(acc[i][j][r]);
  }
}

// -------------------- causal flash attention --------------------
// grid (16 qtiles, 32 heads), 256 threads = 4 waves; wave w owns Q rows w*32..+31.
// Q/K/V sliced straight out of proj (row-major 2048 x 12288 bf16).
__global__ __launch_bounds__(256, 1) void attn_kernel(
    const unsigned short* __restrict__ proj, unsigned short* __restrict__ ao) {
  __shared__ __align__(16) unsigned short Qs[128 * 136];
  __shared__ __align__(16) unsigned short Ks[128 * 136];   // reused as P after QK^T
  __shared__ __align__(16) unsigned short Vts[128 * 136];  // V transposed: [d][key]
  const int qt = blockIdx.x, h = blockIdx.y;
  const int t = threadIdx.x, wave = t >> 6, lane = t & 63;
  const int lq = lane & 15, lg = lane >> 4;

  // stage Q tile (rows qt*128..+127, cols h*128..+127 of proj)
#pragma unroll
  for (int it = 0; it < 8; it++) {
    int idx = t * 8 + it * 2048;
    int r = idx >> 7, c = idx & 127;
    short8 v = *(const short8*)(proj + (long)(qt * 128 + r) * PROJN + h * 128 + c);
    *(short8*)(Qs + r * 136 + c) = v;
  }

  float mrow[2][4], lrow[2][4];
  floatx4 zero = {0.f, 0.f, 0.f, 0.f};
  floatx4 o[2][8];
#pragma unroll
  for (int i = 0; i < 2; i++)
#pragma unroll
    for (int r = 0; r < 4; r++) { mrow[i][r] = -INFINITY; lrow[i][r] = 0.f; }
#pragma unroll
  for (int i = 0; i < 2; i++)
#pragma unroll
    for (int j = 0; j < 8; j++) o[i][j] = zero;

  const float scale = 0.08838834764831845f;  // 1/sqrt(128)

  for (int kv = 0; kv <= qt; kv++) {
    __syncthreads();  // prior P/V reads done (and Q staging on first iter)
    const unsigned short* kbase = proj + (long)(kv * 128) * PROJN + HID + h * 128;
    const unsigned short* vbase = proj + (long)(kv * 128) * PROJN + 2 * HID + h * 128;
#pragma unroll
    for (int it = 0; it < 8; it++) {
      int idx = t * 8 + it * 2048;
      int r = idx >> 7, c = idx & 127;
      short8 kvv = *(const short8*)(kbase + (long)r * PROJN + c);
      *(short8*)(Ks + r * 136 + c) = kvv;
      short8 vv = *(const short8*)(vbase + (long)r * PROJN + c);
#pragma unroll
      for (int j2 = 0; j2 < 8; j2++) Vts[(c + j2) * 136 + r] = (unsigned short)vv[j2];
    }
    __syncthreads();

    // S = Q K^T for this tile: wave rows (2 mtiles), all 128 keys (8 ntiles)
    floatx4 s[2][8];
#pragma unroll
    for (int i = 0; i < 2; i++)
#pragma unroll
      for (int j = 0; j < 8; j++) s[i][j] = zero;
#pragma unroll
    for (int kk = 0; kk < 4; kk++) {
      short8 af[2], bfr[8];
#pragma unroll
      for (int i = 0; i < 2; i++)
        af[i] = *(const short8*)(Qs + (wave * 32 + i * 16 + lq) * 136 + kk * 32 + lg * 8);
#pragma unroll
      for (int j = 0; j < 8; j++)
        bfr[j] = *(const short8*)(Ks + (j * 16 + lq) * 136 + kk * 32 + lg * 8);
#pragma unroll
      for (int i = 0; i < 2; i++)
#pragma unroll
        for (int j = 0; j < 8; j++)
          s[i][j] = __builtin_amdgcn_mfma_f32_16x16x32_bf16(af[i], bfr[j], s[i][j], 0, 0, 0);
    }

    // online softmax (rows are lane-local in C-layout; reduce over 16 col-lanes)
    const bool diag = (kv == qt);
    float alpha_[2][4];
#pragma unroll
    for (int i = 0; i < 2; i++) {
#pragma unroll
      for (int r = 0; r < 4; r++) {
        int qrow = qt * 128 + wave * 32 + i * 16 + lg * 4 + r;
        float mx = -INFINITY;
#pragma unroll
        for (int j = 0; j < 8; j++) {
          float v = s[i][j][r] * scale;
          if (diag && (kv * 128 + j * 16 + lq) > qrow) v = -INFINITY;
          s[i][j][r] = v;
          mx = fmaxf(mx, v);
        }
#pragma unroll
        for (int d = 1; d < 16; d <<= 1) mx = fmaxf(mx, __shfl_xor(mx, d, 64));
        float mnew = fmaxf(mrow[i][r], mx);
        float al = __expf(mrow[i][r] - mnew);
        float ps = 0.f;
#pragma unroll
        for (int j = 0; j < 8; j++) {
          float p = __expf(s[i][j][r] - mnew);
          s[i][j][r] = p;
          ps += p;
        }
#pragma unroll
        for (int d = 1; d < 16; d <<= 1) ps += __shfl_xor(ps, d, 64);
        lrow[i][r] = lrow[i][r] * al + ps;
        mrow[i][r] = mnew;
        alpha_[i][r] = al;
      }
    }
#pragma unroll
    for (int i = 0; i < 2; i++)
#pragma unroll
      for (int j = 0; j < 8; j++)
#pragma unroll
        for (int r = 0; r < 4; r++) o[i][j][r] *= alpha_[i][r];

    __syncthreads();  // all waves done reading Ks before overwrite with P
    // P: C-layout regs -> A-layout via LDS (each wave only touches its own rows)
#pragma unroll
    for (int i = 0; i < 2; i++)
#pragma unroll
      for (int r = 0; r < 4; r++) {
        int prow = wave * 32 + i * 16 + lg * 4 + r;
#pragma unroll
        for (int j = 0; j < 8; j++)
          Ks[prow * 136 + j * 16 + lq] = f2bf(s[i][j][r]);
      }
    // O += P V   (A-frags from own P rows, B-frags from V^T)
#pragma unroll
    for (int kk = 0; kk < 4; kk++) {
      short8 pf[2], vf[8];
#pragma unroll
      for (int i = 0; i < 2; i++)
        pf[i] = *(const short8*)(Ks + (wave * 32 + i * 16 + lq) * 136 + kk * 32 + lg * 8);
#pragma unroll
      for (int j = 0; j < 8; j++)
        vf[j] = *(const short8*)(Vts + (j * 16 + lq) * 136 + kk * 32 + lg * 8);
#pragma unroll
      for (int i = 0; i < 2; i++)
#pragma unroll
        for (int j = 0; j < 8; j++)
          o[i][j] = __builtin_amdgcn_mfma_f32_16x16x32_bf16(pf[i], vf[j], o[i][j], 0, 0, 0);
    }
  }

  // normalize + store attention output: ao[s][h*128 + d] bf16
#pragma unroll
  for (int i = 0; i < 2; i++) {
    float inv[4];
#pragma unroll
    for (int r = 0; r < 4; r++) inv[r] = 1.0f / lrow[i][r];
#pragma unroll
    for (int j = 0; j < 8; j++)
#pragma unroll
      for (int r = 0; r < 4; r++) {
        int row = qt * 128 + wave * 32 + i * 16 + lg * 4 + r;
        int d = j * 16 + lq;
        ao[(long)row * HID + h * 128 + d] = f2bf(o[i][j][r] * inv[r]);
      }
  }
}

// -------------------- launcher --------------------
extern "C" void kernel_launch(void* const* d_in, const int* in_sizes, int n_in,
                              void* d_out, int out_size, void* d_ws, size_t ws_size,
                              hipStream_t stream) {
  (void)in_sizes; (void)n_in; (void)out_size;
  const float* hs = (const float*)d_in[0];
  // d_in[1] = attention_mask: deterministic causal, applied analytically
  const float* wp = (const float*)d_in[2];
  const float* wo = (const float*)d_in[3];
  float* out = (float*)d_out;
  char* ws = (char*)d_ws;

  // ws layout (bytes)
  unsigned short* Xb   = (unsigned short*)(ws);                 // 2048*4096 bf16   (16 MiB)
  unsigned short* Wpb  = (unsigned short*)(ws + 16777216);      // 12288*4096 bf16  (96 MiB)
  unsigned short* Wob  = (unsigned short*)(ws + 117440512);     // 4096*4096 bf16   (32 MiB)
  unsigned short* proj = (unsigned short*)(ws + 150994944);     // 2048*12288 bf16  (48 MiB)
  unsigned short* ao   = (unsigned short*)(ws + 201326592);     // 2048*4096 bf16   (16 MiB)
  if (ws_size < 218103808) return;  // guard: need ~208 MiB scratch

  cvt_kernel<<<8388608 / 2048, 256, 0, stream>>>(hs, Xb);
  cvt_kernel<<<50331648 / 2048, 256, 0, stream>>>(wp, Wpb);
  cvt_kernel<<<16777216 / 2048, 256, 0, stream>>>(wo, Wob);

  gemm_nt<0><<<dim3(96, 16), 256, 0, stream>>>(Xb, Wpb, (void*)proj, SEQ, PROJN, HID);
  attn_kernel<<<dim3(16, 32), 256, 0, stream>>>(proj, ao);
  gemm_nt<1><<<dim3(32, 16), 256, 0, stream>>>(ao, Wob, (void*)out, SEQ, HID, HID);
}

// Round 2
// 1072.649 us; speedup vs baseline: 1.1689x; 1.1689x over previous
//
#include <hip/hip_runtime.h>
#include <stdint.h>

typedef __attribute__((ext_vector_type(8))) short short8;
typedef __attribute__((ext_vector_type(4))) float floatx4;

#define SEQ    2048
#define HID    4096
#define NHEAD  32
#define HDIMV  128
#define PROJN  12288

__device__ __forceinline__ unsigned short f2bf(float f) {
  union { float f; unsigned u; } v; v.f = f;
  unsigned r = (v.u + 0x7fffu + ((v.u >> 16) & 1u)) >> 16;
  return (unsigned short)r;
}

// -------------------- fp32 -> bf16 convert --------------------
__global__ __launch_bounds__(256) void cvt_kernel(const float* __restrict__ src,
                                                  unsigned short* __restrict__ dst) {
  long i = ((long)blockIdx.x * 256 + threadIdx.x) * 8;
  float4 a = *(const float4*)(src + i);
  float4 b = *(const float4*)(src + i + 4);
  short8 o;
  o[0] = (short)f2bf(a.x); o[1] = (short)f2bf(a.y);
  o[2] = (short)f2bf(a.z); o[3] = (short)f2bf(a.w);
  o[4] = (short)f2bf(b.x); o[5] = (short)f2bf(b.y);
  o[6] = (short)f2bf(b.z); o[7] = (short)f2bf(b.w);
  *(short8*)(dst + i) = o;
}

// -------------------- async 16B global->LDS --------------------
__device__ __forceinline__ void g2l16(const void* g, void* l) {
  __builtin_amdgcn_global_load_lds(
      (const __attribute__((address_space(1))) void*)g,
      (__attribute__((address_space(3))) void*)l, 16, 0, 0);
}

// Stage a 128x128 bf16 tile (row pitch `pitch` elems) into chunk-major LDS:
// elem (r,c) -> lds[((c>>3)*128 + r)*8 + (c&7)]. 256 threads, 8 calls each.
__device__ __forceinline__ void stage128(const unsigned short* g, long pitch,
                                         unsigned short* lds, int t) {
  const int sr = t & 127;
  const int skc = (t >> 7) & 1;
  const int wave = t >> 6;
  const unsigned short* gp = g + (long)sr * pitch + skc * 8;
  unsigned short* lp = lds + wave * 512;  // wave-uniform base; HW adds lane*16B
#pragma unroll
  for (int k = 0; k < 8; k++) g2l16(gp + k * 16, lp + k * 2048);
}

// -------------------- NT GEMM: C[MxN] = A[MxK] * B[NxK]^T --------------------
// 128x128 tile, BK=32, 4 waves each 64x64 via 4x4 of 16x16x32 bf16 MFMA.
// Grid: x = m-tile (fastest) so consecutive blocks share one B panel (L2/L3 reuse).
template<int OUT_F32>
__global__ __launch_bounds__(256, 2) void gemm_nt(
    const unsigned short* __restrict__ A,
    const unsigned short* __restrict__ B,
    void* __restrict__ C, int M, int N, int K) {
  __shared__ __align__(16) unsigned short As[4096];
  __shared__ __align__(16) unsigned short Bs[4096];
  const int t = threadIdx.x;
  const int wave = t >> 6;
  const int lane = t & 63;
  const int m0 = blockIdx.x * 128;   // m-tile varies fastest
  const int n0 = blockIdx.y * 128;
  const int c0 = t, c1 = t + 256;
  const unsigned short* a0 = A + (long)(m0 + (c0 & 127)) * K + (c0 >> 7) * 8;
  const unsigned short* a1 = A + (long)(m0 + (c1 & 127)) * K + (c1 >> 7) * 8;
  const unsigned short* b0 = B + (long)(n0 + (c0 & 127)) * K + (c0 >> 7) * 8;
  const unsigned short* b1 = B + (long)(n0 + (c1 & 127)) * K + (c1 >> 7) * 8;
  unsigned short* asl0 = As + wave * 64 * 8;
  unsigned short* asl1 = As + (256 + wave * 64) * 8;
  unsigned short* bsl0 = Bs + wave * 64 * 8;
  unsigned short* bsl1 = Bs + (256 + wave * 64) * 8;

  const int mw = (wave >> 1) * 64;
  const int nw = (wave & 1) * 64;
  const int lq = lane & 15, lg = lane >> 4;
  const int faoff = (lg * 128 + mw + lq) * 8;
  const int fboff = (lg * 128 + nw + lq) * 8;

  floatx4 zero = {0.f, 0.f, 0.f, 0.f};
  floatx4 acc[4][4];
  for (int i = 0; i < 4; i++)
    for (int j = 0; j < 4; j++) acc[i][j] = zero;

  for (int k0 = 0; k0 < K; k0 += 32) {
    __syncthreads();
    g2l16(a0 + k0, asl0);
    g2l16(a1 + k0, asl1);
    g2l16(b0 + k0, bsl0);
    g2l16(b1 + k0, bsl1);
    __syncthreads();
    short8 af[4], bfr[4];
#pragma unroll
    for (int i = 0; i < 4; i++) af[i] = *(const short8*)(As + faoff + i * 128);
#pragma unroll
    for (int j = 0; j < 4; j++) bfr[j] = *(const short8*)(Bs + fboff + j * 128);
#pragma unroll
    for (int i = 0; i < 4; i++)
#pragma unroll
      for (int j = 0; j < 4; j++)
        acc[i][j] = __builtin_amdgcn_mfma_f32_16x16x32_bf16(af[i], bfr[j], acc[i][j], 0, 0, 0);
  }

  const int row0 = m0 + mw + lg * 4;
  const int col0 = n0 + nw + lq;
  if (OUT_F32) {
    float* Cf = (float*)C;
#pragma unroll
    for (int i = 0; i < 4; i++)
#pragma unroll
      for (int j = 0; j < 4; j++)
#pragma unroll
        for (int r = 0; r < 4; r++)
          Cf[(long)(row0 + i * 16 + r) * N + col0 + j * 16] = acc[i][j][r];
  } else {
    unsigned short* Cb = (unsigned short*)C;
#pragma unroll
    for (int i = 0; i < 4; i++)
#pragma unroll
      for (int j = 0; j < 4; j++)
#pragma unroll
        for (int r = 0; r < 4; r++)
          Cb[(long)(row0 + i * 16 + r) * N + col0 + j * 16] = f2bf(acc[i][j][r]);
  }
}

// -------------------- V transpose: proj V-slice -> Vt[h][d][s] --------------------
// grid (16 s-tiles, 32 heads). Coalesced read + coalesced 32B writes.
__global__ __launch_bounds__(256) void vtrans_kernel(const unsigned short* __restrict__ proj,
                                                     unsigned short* __restrict__ Vt) {
  __shared__ unsigned short T[128 * 136];
  const int st = blockIdx.x, h = blockIdx.y, t = threadIdx.x;
  const unsigned short* src = proj + (long)(st * 128) * PROJN + 2 * HID + h * 128;
#pragma unroll
  for (int it = 0; it < 8; it++) {
    int idx = t * 8 + it * 2048;
    int r = idx >> 7, c = idx & 127;
    *(short8*)(T + r * 136 + c) = *(const short8*)(src + (long)r * PROJN + c);
  }
  __syncthreads();
#pragma unroll
  for (int pass = 0; pass < 4; pass++) {
    int d = (t >> 3) + pass * 32;
    int sc = t & 7;
    short8 lo, hi;
#pragma unroll
    for (int j = 0; j < 8; j++)  lo[j] = (short)T[(sc * 16 + j) * 136 + d];
#pragma unroll
    for (int j = 0; j < 8; j++)  hi[j] = (short)T[(sc * 16 + 8 + j) * 136 + d];
    unsigned short* dst = Vt + (long)(h * 128 + d) * 2048 + st * 128 + sc * 16;
    *(short8*)dst = lo;
    *(short8*)(dst + 8) = hi;
  }
}

// -------------------- causal flash attention --------------------
// 256 blocks: h = bx>>3, pair = bx&7 -> q-tiles {15-pair, pair} (17 kv-iters/block,
// perfectly balanced). 4 waves; wave w owns Q rows w*32..+31.
__global__ __launch_bounds__(256, 1) void attn_kernel(
    const unsigned short* __restrict__ proj,
    const unsigned short* __restrict__ Vt,
    unsigned short* __restrict__ ao) {
  __shared__ __align__(16) unsigned short Qs[16384];
  __shared__ __align__(16) unsigned short Ks[16384];
  __shared__ __align__(16) unsigned short Vts[16384];
  __shared__ __align__(16) unsigned short Ps[128 * 136];  // wave-private rows
  const int bx = blockIdx.x;
  const int h = bx >> 3, pr = bx & 7;
  const int t = threadIdx.x, wave = t >> 6, lane = t & 63;
  const int lq = lane & 15, lg = lane >> 4;
  const int wOff = wave * 32;
  const unsigned short* vthead = Vt + (long)h * 128 * 2048;
  // log2-domain softmax: scale' = (1/sqrt(128)) * log2(e)
  const float scale2 = 0.12751744154f;

  for (int ph = 0; ph < 2; ph++) {
    const int qt = ph ? pr : 15 - pr;
    __syncthreads();  // all waves done reading Qs of previous phase
    stage128(proj + (long)(qt * 128) * PROJN + h * 128, PROJN, Qs, t);

    float m2[2][4], lsum[2][4];
    floatx4 zero = {0.f, 0.f, 0.f, 0.f};
    floatx4 o[2][8];
#pragma unroll
    for (int i = 0; i < 2; i++)
#pragma unroll
      for (int r = 0; r < 4; r++) { m2[i][r] = -INFINITY; lsum[i][r] = 0.f; }
#pragma unroll
    for (int i = 0; i < 2; i++)
#pragma unroll
      for (int j = 0; j < 8; j++) o[i][j] = zero;

    for (int kv = 0; kv <= qt; kv++) {
      __syncthreads();  // prior-iter Ks/Vts frag reads complete
      stage128(proj + (long)(kv * 128) * PROJN + HID + h * 128, PROJN, Ks, t);
      stage128(vthead + kv * 128, 2048, Vts, t);
      __syncthreads();  // staging drained (vmcnt(0) before barrier)

      // S = Q K^T : 2 m-frags x 8 n-frags, K-dim = 128 over d
      floatx4 s[2][8];
#pragma unroll
      for (int i = 0; i < 2; i++)
#pragma unroll
        for (int j = 0; j < 8; j++) s[i][j] = zero;
#pragma unroll
      for (int kk = 0; kk < 4; kk++) {
        const int ch = (kk * 4) * 128 * 8;  // + lg*128*8 below
        short8 af[2], bfr[8];
#pragma unroll
        for (int i = 0; i < 2; i++)
          af[i] = *(const short8*)(Qs + ch + (lg * 128 + wOff + i * 16 + lq) * 8);
#pragma unroll
        for (int j = 0; j < 8; j++)
          bfr[j] = *(const short8*)(Ks + ch + (lg * 128 + j * 16 + lq) * 8);
#pragma unroll
        for (int i = 0; i < 2; i++)
#pragma unroll
          for (int j = 0; j < 8; j++)
            s[i][j] = __builtin_amdgcn_mfma_f32_16x16x32_bf16(af[i], bfr[j], s[i][j], 0, 0, 0);
      }

      // online softmax in exp2 domain (rows lane-local; reduce over 16 col-lanes)
      const bool diag = (kv == qt);
      float alpha_[2][4];
#pragma unroll
      for (int i = 0; i < 2; i++) {
#pragma unroll
        for (int r = 0; r < 4; r++) {
          int qrow = qt * 128 + wOff + i * 16 + lg * 4 + r;
          float mx = -INFINITY;
#pragma unroll
          for (int j = 0; j < 8; j++) {
            float v = s[i][j][r] * scale2;
            if (diag && (kv * 128 + j * 16 + lq) > qrow) v = -INFINITY;
            s[i][j][r] = v;
            mx = fmaxf(mx, v);
          }
#pragma unroll
          for (int d = 1; d < 16; d <<= 1) mx = fmaxf(mx, __shfl_xor(mx, d, 64));
          float mnew = fmaxf(m2[i][r], mx);
          float al = exp2f(m2[i][r] - mnew);
          float ps = 0.f;
#pragma unroll
          for (int j = 0; j < 8; j++) {
            float p = exp2f(s[i][j][r] - mnew);
            s[i][j][r] = p;
            ps += p;
          }
#pragma unroll
          for (int d = 1; d < 16; d <<= 1) ps += __shfl_xor(ps, d, 64);
          lsum[i][r] = lsum[i][r] * al + ps;
          m2[i][r] = mnew;
          alpha_[i][r] = al;
        }
      }
#pragma unroll
      for (int i = 0; i < 2; i++)
#pragma unroll
        for (int j = 0; j < 8; j++)
#pragma unroll
          for (int r = 0; r < 4; r++) o[i][j][r] *= alpha_[i][r];

      // P (C-layout regs) -> A-layout LDS; wave-private rows, no barrier needed
#pragma unroll
      for (int i = 0; i < 2; i++)
#pragma unroll
        for (int r = 0; r < 4; r++) {
          int prow = wOff + i * 16 + lg * 4 + r;
#pragma unroll
          for (int j = 0; j < 8; j++)
            Ps[prow * 136 + j * 16 + lq] = f2bf(s[i][j][r]);
        }

      // O += P V : A-frags from own P rows, B-frags from Vt (chunk-major, k=key)
#pragma unroll
      for (int kk = 0; kk < 4; kk++) {
        short8 pf[2], vf[8];
#pragma unroll
        for (int i = 0; i < 2; i++)
          pf[i] = *(const short8*)(Ps + (wOff + i * 16 + lq) * 136 + kk * 32 + lg * 8);
#pragma unroll
        for (int j = 0; j < 8; j++)
          vf[j] = *(const short8*)(Vts + ((kk * 4 + lg) * 128 + j * 16 + lq) * 8);
#pragma unroll
        for (int i = 0; i < 2; i++)
#pragma unroll
          for (int j = 0; j < 8; j++)
            o[i][j] = __builtin_amdgcn_mfma_f32_16x16x32_bf16(pf[i], vf[j], o[i][j], 0, 0, 0);
      }
    }

    // epilogue: normalize, pack via wave-private Ps rows, coalesced 16B stores
#pragma unroll
    for (int i = 0; i < 2; i++) {
      float inv[4];
#pragma unroll
      for (int r = 0; r < 4; r++) inv[r] = 1.0f / lsum[i][r];
#pragma unroll
      for (int r = 0; r < 4; r++) {
        int prow = wOff + i * 16 + lg * 4 + r;
#pragma unroll
        for (int j = 0; j < 8; j++)
          Ps[prow * 136 + j * 16 + lq] = f2bf(o[i][j][r] * inv[r]);
      }
    }
#pragma unroll
    for (int it = 0; it < 8; it++) {
      int idx = it * 64 + lane;
      int row_loc = idx >> 4, c8 = idx & 15;
      short8 v = *(const short8*)(Ps + (wOff + row_loc) * 136 + c8 * 8);
      *(short8*)(ao + (long)(qt * 128 + wOff + row_loc) * HID + h * 128 + c8 * 8) = v;
    }
  }
}

// -------------------- launcher --------------------
extern "C" void kernel_launch(void* const* d_in, const int* in_sizes, int n_in,
                              void* d_out, int out_size, void* d_ws, size_t ws_size,
                              hipStream_t stream) {
  (void)in_sizes; (void)n_in; (void)out_size;
  const float* hs = (const float*)d_in[0];
  // d_in[1] = attention_mask: deterministic causal, applied analytically
  const float* wp = (const float*)d_in[2];
  const float* wo = (const float*)d_in[3];
  float* out = (float*)d_out;
  char* ws = (char*)d_ws;

  // ws layout (bytes); Vt reuses Xb region (X consumed by gemm1 before vtrans)
  unsigned short* Xb   = (unsigned short*)(ws);                 // 2048*4096 bf16   (16 MiB)
  unsigned short* Wpb  = (unsigned short*)(ws + 16777216);      // 12288*4096 bf16  (96 MiB)
  unsigned short* Wob  = (unsigned short*)(ws + 117440512);     // 4096*4096 bf16   (32 MiB)
  unsigned short* proj = (unsigned short*)(ws + 150994944);     // 2048*12288 bf16  (48 MiB)
  unsigned short* ao   = (unsigned short*)(ws + 201326592);     // 2048*4096 bf16   (16 MiB)
  unsigned short* Vt   = Xb;                                    // 32*128*2048 bf16 (16 MiB)
  if (ws_size < 218103808) return;  // guard: need ~208 MiB scratch

  cvt_kernel<<<8388608 / 2048, 256, 0, stream>>>(hs, Xb);
  cvt_kernel<<<50331648 / 2048, 256, 0, stream>>>(wp, Wpb);
  cvt_kernel<<<16777216 / 2048, 256, 0, stream>>>(wo, Wob);

  gemm_nt<0><<<dim3(16, 96), 256, 0, stream>>>(Xb, Wpb, (void*)proj, SEQ, PROJN, HID);
  vtrans_kernel<<<dim3(16, 32), 256, 0, stream>>>(proj, Vt);
  attn_kernel<<<256, 256, 0, stream>>>(proj, Vt, ao);
  gemm_nt<1><<<dim3(16, 32), 256, 0, stream>>>(ao, Wob, (void*)out, SEQ, HID, HID);
}